// Round 1
// baseline (901.945 us; speedup 1.0000x reference)
//
#include <hip/hip_runtime.h>
#include <stdint.h>

#define S 2048
#define D 64
#define NKT (S / 64)     // 32 key tiles of 64
#define SCALEF 0.125f    // 1/sqrt(64)

typedef __attribute__((ext_vector_type(8))) _Float16 half8;
typedef __attribute__((ext_vector_type(4))) _Float16 half4;
typedef __attribute__((ext_vector_type(4))) float floatx4;

__device__ __forceinline__ float redmax16(float x) {
#pragma unroll
  for (int off = 8; off >= 1; off >>= 1) x = fmaxf(x, __shfl_xor(x, off, 16));
  return x;
}
__device__ __forceinline__ float redsum16(float x) {
#pragma unroll
  for (int off = 8; off >= 1; off >>= 1) x += __shfl_xor(x, off, 16);
  return x;
}

// elementwise f32 -> f16 (for K), 1 float4 per thread
__global__ __launch_bounds__(256) void conv_f16_kernel(const floatx4* __restrict__ src,
                                                       half4* __restrict__ dst) {
  int i = blockIdx.x * 256 + threadIdx.x;
  floatx4 v = src[i];
  half4 h;
  h[0] = (_Float16)v[0];
  h[1] = (_Float16)v[1];
  h[2] = (_Float16)v[2];
  h[3] = (_Float16)v[3];
  dst[i] = h;
}

// V [bh][key][d] f32 -> Vt [bh][d][key] f16 (LDS tile transpose)
__global__ __launch_bounds__(256) void conv_vt_kernel(const float* __restrict__ v,
                                                      _Float16* __restrict__ vt) {
  __shared__ float tile[64][65];
  int bh = blockIdx.x >> 5;
  int kt = blockIdx.x & 31;
  const float* src = v + ((size_t)bh * S + (size_t)kt * 64) * D;
#pragma unroll
  for (int i = 0; i < 16; i++) {
    int idx = threadIdx.x + 256 * i;
    tile[idx >> 6][idx & 63] = src[idx];
  }
  __syncthreads();
  _Float16* dst = vt + (size_t)bh * D * S + kt * 64;
#pragma unroll
  for (int i = 0; i < 16; i++) {
    int idx = threadIdx.x + 256 * i;
    int d = idx >> 6;
    int ky = idx & 63;
    dst[(size_t)d * S + ky] = (_Float16)tile[ky][d];
  }
}

// mask [r][key] int32 -> packed [r][kt][c] u32, byte nt = mask[r][64*kt + 16*nt + c]
__global__ __launch_bounds__(256) void pack_mask_kernel(const int* __restrict__ mask,
                                                        uint32_t* __restrict__ mp) {
  int i = blockIdx.x * 256 + threadIdx.x;  // 2048*32*16 = 1M outputs
  int c = i & 15;
  int kt = (i >> 4) & 31;
  int r = i >> 9;
  const int* row = mask + (size_t)r * S + kt * 64 + c;
  uint32_t b0 = (uint32_t)(row[0] != 0);
  uint32_t b1 = (uint32_t)(row[16] != 0);
  uint32_t b2 = (uint32_t)(row[32] != 0);
  uint32_t b3 = (uint32_t)(row[48] != 0);
  mp[i] = b0 | (b1 << 8) | (b2 << 16) | (b3 << 24);
}

// Fused attention. Block = 256 thr = 4 waves; each wave owns 16 q-rows.
// MFMA 16x16x32 f16: A[m=lane&15][k=quad*8+j], B[k=quad*8+j][n=lane&15],
// C/D: col=lane&15, row=quad*4+reg  (per verified gfx950 layouts).
__global__ __launch_bounds__(256, 4) void attn_kernel(
    const float* __restrict__ q, const _Float16* __restrict__ kh,
    const _Float16* __restrict__ vt, const uint32_t* __restrict__ mp,
    float* __restrict__ out_o, float* __restrict__ out_attn) {
  const int bh = blockIdx.x >> 5;
  const int qt = blockIdx.x & 31;
  const int lane = threadIdx.x & 63;
  const int wid = threadIdx.x >> 6;
  const int c16 = lane & 15;
  const int quad = lane >> 4;
  const int rowbase = qt * 64 + wid * 16;

  // Q fragments (A-operand), resident: aq[ch][j] = Q[rowbase+c16][ch*32+quad*8+j]
  half8 aq[2];
  {
    const float* qrow = q + ((size_t)bh * S + rowbase + c16) * D + quad * 8;
#pragma unroll
    for (int ch = 0; ch < 2; ch++) {
      const floatx4* p4 = (const floatx4*)(qrow + ch * 32);
      floatx4 f0 = p4[0];
      floatx4 f1 = p4[1];
      half8 h;
      h[0] = (_Float16)f0[0]; h[1] = (_Float16)f0[1];
      h[2] = (_Float16)f0[2]; h[3] = (_Float16)f0[3];
      h[4] = (_Float16)f1[0]; h[5] = (_Float16)f1[1];
      h[6] = (_Float16)f1[2]; h[7] = (_Float16)f1[3];
      aq[ch] = h;
    }
  }

  const _Float16* kbase = kh + ((size_t)bh * S + c16) * D + quad * 8;
  const uint32_t* mbase = mp + ((size_t)(rowbase + 4 * quad) * NKT) * 16 + c16;

  float m_run[4], l_run[4];
#pragma unroll
  for (int r = 0; r < 4; r++) { m_run[r] = -1e30f; l_run[r] = 0.0f; }

  // ---------- pass 1: row max + denominator ----------
#pragma unroll 1
  for (int kt = 0; kt < NKT; kt++) {
    floatx4 acc[4];
#pragma unroll
    for (int nt = 0; nt < 4; nt++) {
      floatx4 a = {0.0f, 0.0f, 0.0f, 0.0f};
#pragma unroll
      for (int ch = 0; ch < 2; ch++) {
        half8 b = *(const half8*)(kbase + ((size_t)kt * 64 + nt * 16) * D + ch * 32);
        a = __builtin_amdgcn_mfma_f32_16x16x32_f16(aq[ch], b, a, 0, 0, 0);
      }
      acc[nt] = a;
    }
#pragma unroll
    for (int r = 0; r < 4; r++) {
      uint32_t mb = mbase[((size_t)r * NKT + kt) * 16];
      float s[4];
      float tmax = -1e30f;
#pragma unroll
      for (int nt = 0; nt < 4; nt++) {
        s[nt] = acc[nt][r] * SCALEF;
        float sm = ((mb >> (8 * nt)) & 1u) ? s[nt] : -1e30f;
        tmax = fmaxf(tmax, sm);
      }
      tmax = redmax16(tmax);
      float mnew = fmaxf(m_run[r], tmax);
      float ts = 0.0f;
#pragma unroll
      for (int nt = 0; nt < 4; nt++) {
        float p = ((mb >> (8 * nt)) & 1u) ? __expf(s[nt] - mnew) : 0.0f;
        ts += p;
      }
      ts = redsum16(ts);
      l_run[r] = l_run[r] * __expf(m_run[r] - mnew) + ts;
      m_run[r] = mnew;
    }
  }

  float inv_l[4];
#pragma unroll
  for (int r = 0; r < 4; r++) inv_l[r] = 1.0f / l_run[r];

  // ---------- pass 2: recompute S, write attn, accumulate O = P*V ----------
  __shared__ __align__(16) _Float16 plds[4][16][72];  // per-wave P tile, ld=72 (16B-aligned rows)
  floatx4 oacc[4];
#pragma unroll
  for (int nt = 0; nt < 4; nt++) oacc[nt] = (floatx4){0.0f, 0.0f, 0.0f, 0.0f};

  float* attn_base = out_attn + ((size_t)bh * S + rowbase + 4 * quad) * S + c16;
  const _Float16* vbase = vt + (size_t)bh * D * S + (size_t)c16 * S + quad * 8;

#pragma unroll 1
  for (int kt = 0; kt < NKT; kt++) {
    floatx4 acc[4];
#pragma unroll
    for (int nt = 0; nt < 4; nt++) {
      floatx4 a = {0.0f, 0.0f, 0.0f, 0.0f};
#pragma unroll
      for (int ch = 0; ch < 2; ch++) {
        half8 b = *(const half8*)(kbase + ((size_t)kt * 64 + nt * 16) * D + ch * 32);
        a = __builtin_amdgcn_mfma_f32_16x16x32_f16(aq[ch], b, a, 0, 0, 0);
      }
      acc[nt] = a;
    }
#pragma unroll
    for (int r = 0; r < 4; r++) {
      uint32_t mb = mbase[((size_t)r * NKT + kt) * 16];
#pragma unroll
      for (int nt = 0; nt < 4; nt++) {
        float sv = acc[nt][r] * SCALEF;
        float p = ((mb >> (8 * nt)) & 1u) ? __expf(sv - m_run[r]) : 0.0f;
        float av = p * inv_l[r];
        attn_base[(size_t)r * S + kt * 64 + nt * 16] = av;  // coalesced across c16
        plds[wid][4 * quad + r][nt * 16 + c16] = (_Float16)av;
      }
    }
    // wave-internal LDS drain: writes done before cross-lane fragment reads
    __asm__ volatile("s_waitcnt lgkmcnt(0)" ::: "memory");
    half8 a2[2];
#pragma unroll
    for (int c2 = 0; c2 < 2; c2++)
      a2[c2] = *(const half8*)&plds[wid][c16][c2 * 32 + quad * 8];
#pragma unroll
    for (int nt = 0; nt < 4; nt++) {  // nt tiles the d dimension of O
      floatx4 o = oacc[nt];
#pragma unroll
      for (int c2 = 0; c2 < 2; c2++) {
        half8 b2 = *(const half8*)(vbase + (size_t)nt * 16 * S + kt * 64 + c2 * 32);
        o = __builtin_amdgcn_mfma_f32_16x16x32_f16(a2[c2], b2, o, 0, 0, 0);
      }
      oacc[nt] = o;
    }
    // WAR guard before next iteration's plds writes
    __asm__ volatile("s_waitcnt lgkmcnt(0)" ::: "memory");
  }

  // write O (C-layout: row=4*quad+r, col=d=nt*16+c16)
  float* obase = out_o + ((size_t)bh * S + rowbase + 4 * quad) * D + c16;
#pragma unroll
  for (int nt = 0; nt < 4; nt++)
#pragma unroll
    for (int r = 0; r < 4; r++)
      obase[(size_t)r * D + nt * 16] = oacc[nt][r];
}

extern "C" void kernel_launch(void* const* d_in, const int* in_sizes, int n_in,
                              void* d_out, int out_size, void* d_ws, size_t ws_size,
                              hipStream_t stream) {
  const float* q = (const float*)d_in[0];
  const float* k = (const float*)d_in[1];
  const float* v = (const float*)d_in[2];
  const int* mask = (const int*)d_in[3];

  char* ws = (char*)d_ws;
  _Float16* kh = (_Float16*)ws;               // 32*2048*64*2 = 8,388,608 B
  _Float16* vt = (_Float16*)(ws + 8388608);   // 8,388,608 B
  uint32_t* mp = (uint32_t*)(ws + 16777216);  // 4,194,304 B  (total 20 MiB)

  float* out_o = (float*)d_out;                       // [2,16,2048,64]
  float* out_attn = out_o + (size_t)32 * S * D;       // [2,16,2048,2048]

  conv_f16_kernel<<<4096, 256, 0, stream>>>((const floatx4*)k, (half4*)kh);
  conv_vt_kernel<<<1024, 256, 0, stream>>>(v, vt);
  pack_mask_kernel<<<4096, 256, 0, stream>>>(mask, mp);
  attn_kernel<<<1024, 256, 0, stream>>>(q, kh, vt, mp, out_o, out_attn);
}